// Round 10
// baseline (160.795 us; speedup 1.0000x reference)
//
#include <hip/hip_runtime.h>
#include <hip/hip_bf16.h>

#define B_ 8
#define C_ 64
#define H_ 128
#define W_ 128
#define HW_ (H_ * W_)

typedef __attribute__((ext_vector_type(8))) _Float16 half8v;
typedef __attribute__((ext_vector_type(4))) float float4v;
typedef _Float16 f16x2 __attribute__((ext_vector_type(2)));

// f16x2 pair-dot with f32 accumulate (v_dot2_f32_f16).
static __device__ inline float dot2(unsigned a, unsigned b, float c) {
    f16x2 ha, hb;
    __builtin_memcpy(&ha, &a, 4);
    __builtin_memcpy(&hb, &b, 4);
#if __has_builtin(__builtin_amdgcn_fdot2)
    return __builtin_amdgcn_fdot2(ha, hb, c, false);
#else
    return fmaf((float)ha.x, (float)hb.x, fmaf((float)ha.y, (float)hb.y, c));
#endif
}

static __device__ inline float2 up2(unsigned u) {
    f16x2 h;
    __builtin_memcpy(&h, &u, 4);
    return make_float2((float)h.x, (float)h.y);
}

#define HP_ 484                 // 22*22 halo pixels
#define PL_ 1948                // words per uint4-plane (484*4 + 12 pad)

// ---------------------------------------------------------------------------
// proj_stage: MFMA-compute a 64-ch 1x1-conv projection (W 64x64 fp32,
// fp16 2-term x = xh + xl, swapped operands: mfma(W_frag, x_frag) ->
// D[o][px]) for a set of tile pixel slots, writing fp16 [px][64ch] into the
// LDS tile. Bit-identical math to the R9 proj kernel (same fragment
// construction, same hi->lo MFMA order, same fp16 rounding on write).
// HALO=true: 31 m-tiles over the 484 halo px (x=0 for OOB -> k/v=0,
// matching zero-pad). HALO=false: 16 m-tiles over the own 256 px (for q).
// x is read directly from global (16 MB, L2/L3-resident; fragment rows are
// ~64B-contiguous across lanes). unroll 1 keeps the live set ~45 regs.
// ---------------------------------------------------------------------------
template<bool HALO>
static __device__ inline void proj_stage(
    const float* __restrict__ xb, const float* __restrict__ wmat,
    float* tile, int h0, int w0, int wave, int lane)
{
    const int n = lane & 15, kg = lane >> 4;
    const int NMT = HALO ? 31 : 16;
    #pragma unroll 1
    for (int m = wave; m < NMT; m += 8) {
        const int pxn = m * 16 + n;
        bool val;
        size_t gofs;
        if (HALO) {
            const int r = pxn / 22, cl = pxn - r * 22;
            const int gh = h0 + r - 3, gw = w0 + cl - 3;
            val = (pxn < HP_) && (gh >= 0) && (gh < H_) && (gw >= 0) && (gw < W_);
            gofs = val ? (size_t)(gh * W_ + gw) : 0;
        } else {
            val = true;
            gofs = (size_t)((h0 + (pxn >> 4)) * W_ + w0 + (pxn & 15));
        }
        float4v acc[4];
        #pragma unroll
        for (int nt = 0; nt < 4; ++nt) acc[nt] = (float4v){0.f, 0.f, 0.f, 0.f};
        #pragma unroll
        for (int ks = 0; ks < 2; ++ks) {
            half8v ah, al;
            #pragma unroll
            for (int j = 0; j < 8; ++j) {
                const float f = val ? xb[(size_t)(ks * 32 + kg * 8 + j) * HW_ + gofs] : 0.f;
                const _Float16 h = (_Float16)f;
                ah[j] = h;
                al[j] = (_Float16)(f - (float)h);
            }
            #pragma unroll
            for (int nt = 0; nt < 4; ++nt) {
                const float* wrow = wmat + (nt * 16 + n) * 64 + ks * 32 + kg * 8;
                const float4 wa = *(const float4*)wrow;
                const float4 wc = *(const float4*)(wrow + 4);
                half8v wf;
                wf[0] = (_Float16)wa.x; wf[1] = (_Float16)wa.y;
                wf[2] = (_Float16)wa.z; wf[3] = (_Float16)wa.w;
                wf[4] = (_Float16)wc.x; wf[5] = (_Float16)wc.y;
                wf[6] = (_Float16)wc.z; wf[7] = (_Float16)wc.w;
                acc[nt] = __builtin_amdgcn_mfma_f32_16x16x32_f16(wf, ah, acc[nt], 0, 0, 0);
                acc[nt] = __builtin_amdgcn_mfma_f32_16x16x32_f16(wf, al, acc[nt], 0, 0, 0);
            }
        }
        // D: col = n = pixel, row = kg*4+r = channel -> 4 consecutive
        // channels of one pixel = one 8-B LDS write into [px][64ch] layout.
        if (!HALO || pxn < HP_) {
            #pragma unroll
            for (int nt = 0; nt < 4; ++nt) {
                const int c8 = nt * 2 + (kg >> 1);
                f16x2 lo = {(_Float16)acc[nt][0], (_Float16)acc[nt][1]};
                f16x2 hi = {(_Float16)acc[nt][2], (_Float16)acc[nt][3]};
                uint2 u;
                __builtin_memcpy(&u.x, &lo, 4);
                __builtin_memcpy(&u.y, &hi, 4);
                *(uint2*)(tile + c8 * PL_ + pxn * 4 + (kg & 1) * 2) = u;
            }
        }
    }
}

// ---------------------------------------------------------------------------
// Fully fused QKV-projection + local attention. Eliminates the proj kernel,
// its 50 MB q/k/v HBM write + 67 MB re-read, one launch, and all workspace.
// Per block: [MFMA q -> LDS, read qv] [MFMA k-halo -> LDS] [phase 1 scores,
// butterfly, softmax] [MFMA v-halo -> LDS] [phase 2 + store]. Attn phases
// are byte-identical to R9 (channel-split pairs, dot2, xor-1 merge). 5
// barriers, strict phase separation (R1/R3 spill lessons). LDS 62.3 KB ->
// 2 blocks/CU; co-resident blocks overlap LDS-bound attn phases with
// global+MFMA proj stages. grid (8,8,8) x 512 thr.
// ---------------------------------------------------------------------------
__global__ __launch_bounds__(512, 4) void fused_attn(
    const float* __restrict__ x,
    const float* __restrict__ w1, const float* __restrict__ w2,
    const float* __restrict__ w3, float* __restrict__ out)
{
    __shared__ float tile[8 * PL_];
    const int b = blockIdx.z, h0 = blockIdx.y * 16, w0 = blockIdx.x * 16;
    const int t = threadIdx.x;
    const int lane = t & 63, wave = t >> 6;
    const int g = lane & 1;                      // channel-group: planes g*4..g*4+3
    const int pixel = wave * 32 + (lane >> 1);   // 0..255
    const int pw = pixel & 15, ph = pixel >> 4;
    const size_t px = (size_t)(h0 + ph) * W_ + (w0 + pw);
    const float* xb = x + (size_t)b * C_ * HW_;

    // ---- q stage: own 256 px into tile slots [ownpx][64ch] ----
    proj_stage<false>(xb, w1, tile, h0, w0, wave, lane);
    __syncthreads();
    uint4 qv[4];
    #pragma unroll
    for (int pp = 0; pp < 4; ++pp)
        qv[pp] = *(const uint4*)(tile + (g * 4 + pp) * PL_ + pixel * 4);
    __syncthreads();            // qv read before k overwrites

    // ---- k stage: 484-px halo into the tile ----
    proj_stage<true>(xb, w2, tile, h0, w0, wave, lane);
    __syncthreads();

    // ---- phase 1: partial scores over own 4 planes ----
    float sc[49];
    #pragma unroll
    for (int dh = 0; dh < 7; ++dh) {
        #pragma unroll
        for (int dw = 0; dw < 7; ++dw) {
            const int np = ((ph + dh) * 22 + (pw + dw)) * 4;
            float s0 = 0.f, s1 = 0.f, s2 = 0.f, s3 = 0.f;
            #pragma unroll
            for (int pp = 0; pp < 4; ++pp) {
                const uint4 u = *(const uint4*)(tile + (g * 4 + pp) * PL_ + np);
                s0 = dot2(qv[pp].x, u.x, s0);
                s1 = dot2(qv[pp].y, u.y, s1);
                s2 = dot2(qv[pp].z, u.z, s2);
                s3 = dot2(qv[pp].w, u.w, s3);
            }
            sc[dh * 7 + dw] = (s0 + s1) + (s2 + s3);
        }
    }

    // ---- merge pair partials: xor-1 butterfly ----
    #pragma unroll
    for (int i = 0; i < 49; ++i)
        sc[i] += __shfl_xor(sc[i], 1, 64);

    // ---- softmax over 49 (duplicated per pair) ----
    float m = sc[0];
    #pragma unroll
    for (int i = 1; i < 49; ++i) m = fmaxf(m, sc[i]);
    float s = 0.f;
    #pragma unroll
    for (int i = 0; i < 49; ++i) { sc[i] = __expf(sc[i] - m); s += sc[i]; }
    const float inv = 1.f / s;
    #pragma unroll
    for (int i = 0; i < 49; ++i) sc[i] *= inv;

    __syncthreads();            // all phase-1 reads done before v overwrites

    // ---- v stage: 484-px halo into the tile ----
    proj_stage<true>(xb, w3, tile, h0, w0, wave, lane);
    __syncthreads();

    // ---- phase 2: weighting over own 4 planes (acc[32]) ----
    float acc[32];
    #pragma unroll
    for (int c = 0; c < 32; ++c) acc[c] = 0.f;
    #pragma unroll
    for (int dh = 0; dh < 7; ++dh) {
        #pragma unroll
        for (int dw = 0; dw < 7; ++dw) {
            const float wgt = sc[dh * 7 + dw];
            const int np = ((ph + dh) * 22 + (pw + dw)) * 4;
            #pragma unroll
            for (int pp = 0; pp < 4; ++pp) {
                const uint4 u = *(const uint4*)(tile + (g * 4 + pp) * PL_ + np);
                const int a = pp * 8;
                float2 f;
                f = up2(u.x); acc[a + 0] = fmaf(wgt, f.x, acc[a + 0]);
                              acc[a + 1] = fmaf(wgt, f.y, acc[a + 1]);
                f = up2(u.y); acc[a + 2] = fmaf(wgt, f.x, acc[a + 2]);
                              acc[a + 3] = fmaf(wgt, f.y, acc[a + 3]);
                f = up2(u.z); acc[a + 4] = fmaf(wgt, f.x, acc[a + 4]);
                              acc[a + 5] = fmaf(wgt, f.y, acc[a + 5]);
                f = up2(u.w); acc[a + 6] = fmaf(wgt, f.x, acc[a + 6]);
                              acc[a + 7] = fmaf(wgt, f.y, acc[a + 7]);
            }
        }
    }

    // ---- store own 32 channels: [b][64][HW] ----
    #pragma unroll
    for (int pp = 0; pp < 4; ++pp) {
        const int p8 = g * 4 + pp;
        const int ch0 = (p8 >> 1) * 16 + (p8 & 1) * 8;
        #pragma unroll
        for (int j = 0; j < 8; ++j)
            out[((size_t)b * 64 + ch0 + j) * HW_ + px] = acc[pp * 8 + j];
    }
}

extern "C" void kernel_launch(void* const* d_in, const int* in_sizes, int n_in,
                              void* d_out, int out_size, void* d_ws, size_t ws_size,
                              hipStream_t stream) {
    const float* x  = (const float*)d_in[0];
    const float* w1 = (const float*)d_in[1];
    const float* w2 = (const float*)d_in[2];
    const float* w3 = (const float*)d_in[3];
    float* o = (float*)d_out;

    fused_attn<<<dim3(W_ / 16, H_ / 16, B_), 512, 0, stream>>>(x, w1, w2, w3, o);
}

// Round 13
// 138.865 us; speedup vs baseline: 1.1579x; 1.1579x over previous
//
#include <hip/hip_runtime.h>
#include <hip/hip_bf16.h>

#define B_ 8
#define C_ 64
#define H_ 128
#define W_ 128
#define HW_ (H_ * W_)

typedef __attribute__((ext_vector_type(8))) _Float16 half8v;
typedef __attribute__((ext_vector_type(4))) float float4v;
typedef _Float16 f16x2 __attribute__((ext_vector_type(2)));

// f16x2 pair-dot with f32 accumulate (v_dot2_f32_f16).
static __device__ inline float dot2(unsigned a, unsigned b, float c) {
    f16x2 ha, hb;
    __builtin_memcpy(&ha, &a, 4);
    __builtin_memcpy(&hb, &b, 4);
#if __has_builtin(__builtin_amdgcn_fdot2)
    return __builtin_amdgcn_fdot2(ha, hb, c, false);
#else
    return fmaf((float)ha.x, (float)hb.x, fmaf((float)ha.y, (float)hb.y, c));
#endif
}

static __device__ inline float2 up2(unsigned u) {
    f16x2 h;
    __builtin_memcpy(&h, &u, 4);
    return make_float2((float)h.x, (float)h.y);
}

// ---------------------------------------------------------------------------
// K1: QKV projection (R9 version — proven ~proj-floor). fp16 2-term
// (x = xh + xl, W single fp16), swapped-operand MFMA (D[o][px]) -> coalesced
// uint2 stores; W loaded inline from w1/w2/w3; x staged via xt[pxg][260]
// (conflict-free writes AND reads). R10 calibration: proj ≈ 22 us vs ~14 us
// traffic floor — five tuning theories null because there's little left.
// ---------------------------------------------------------------------------
#define XG_ 260                  // words per px-group row (64 ch * 4 + 4 pad)

__global__ __launch_bounds__(512, 4) void proj_qkv(
    const float* __restrict__ x,
    const float* __restrict__ w1, const float* __restrict__ w2,
    const float* __restrict__ w3,
    _Float16* __restrict__ q, _Float16* __restrict__ k, _Float16* __restrict__ v)
{
    __shared__ float xt[32 * XG_];
    const int b = blockIdx.y;
    const int px0 = blockIdx.x * 128;
    const int t = threadIdx.x;
    const int lane = t & 63;
    const int wave = t >> 6;                 // 0..7
    const int wave_m = wave & 1, wave_n = wave >> 1;   // 2 x 4
    const int n = lane & 15, kg = lane >> 4;

    // ---- stage x tile: [c][128px] global -> [pxg][c] LDS (float4 cells) ----
    const float* xb = x + (size_t)b * C_ * HW_;
    #pragma unroll
    for (int r = 0; r < 4; ++r) {
        const int fi = t + r * 512;          // 2048 float4s total
        const int pxg = fi & 31;             // 32 px-groups of 4
        const int c = fi >> 5;               // channel
        const float4 val = *(const float4*)(xb + (size_t)c * HW_ + px0 + pxg * 4);
        *(float4*)(xt + pxg * XG_ + c * 4) = val;
    }
    __syncthreads();

    float4v acc[3][4];
    #pragma unroll
    for (int tnt = 0; tnt < 3; ++tnt)
        #pragma unroll
        for (int mt = 0; mt < 4; ++mt)
            acc[tnt][mt] = (float4v){0.f, 0.f, 0.f, 0.f};

    const int pxl = wave_m * 64 + n;         // local px base

    #pragma unroll
    for (int ks = 0; ks < 2; ++ks) {
        half8v ah[4], al[4];
        #pragma unroll
        for (int mt = 0; mt < 4; ++mt) {
            const int px = pxl + mt * 16;
            const float* xp = xt + (px >> 2) * XG_ + (px & 3) + (ks * 32 + kg * 8) * 4;
            #pragma unroll
            for (int j = 0; j < 8; ++j) {
                const float f = xp[j * 4];
                const _Float16 h = (_Float16)f;
                ah[mt][j] = h;
                al[mt][j] = (_Float16)(f - (float)h);
            }
        }
        // W fragments for this ks: o = (gnt&3)*16 + n of wsel, c = ks*32+kg*8+j
        half8v wfr[3];
        #pragma unroll
        for (int tnt = 0; tnt < 3; ++tnt) {
            const int gnt = wave_n * 3 + tnt;
            const float* wsel = (gnt < 4) ? w1 : (gnt < 8) ? w2 : w3;
            const float* wrow = wsel + ((gnt & 3) * 16 + n) * 64 + ks * 32 + kg * 8;
            const float4 wa = *(const float4*)wrow;
            const float4 wc = *(const float4*)(wrow + 4);
            wfr[tnt][0] = (_Float16)wa.x; wfr[tnt][1] = (_Float16)wa.y;
            wfr[tnt][2] = (_Float16)wa.z; wfr[tnt][3] = (_Float16)wa.w;
            wfr[tnt][4] = (_Float16)wc.x; wfr[tnt][5] = (_Float16)wc.y;
            wfr[tnt][6] = (_Float16)wc.z; wfr[tnt][7] = (_Float16)wc.w;
        }
        #pragma unroll
        for (int tnt = 0; tnt < 3; ++tnt) {
            #pragma unroll
            for (int mt = 0; mt < 4; ++mt) {
                acc[tnt][mt] = __builtin_amdgcn_mfma_f32_16x16x32_f16(
                    wfr[tnt], ah[mt], acc[tnt][mt], 0, 0, 0);
                acc[tnt][mt] = __builtin_amdgcn_mfma_f32_16x16x32_f16(
                    wfr[tnt], al[mt], acc[tnt][mt], 0, 0, 0);
            }
        }
    }

    // epilogue (transposed D): col = n = pixel, row = kg*4+r = channel.
    // 4 consecutive channels of one pixel -> one 8-B uint2 store.
    #pragma unroll
    for (int tnt = 0; tnt < 3; ++tnt) {
        const int gnt = wave_n * 3 + tnt;              // wave-uniform
        _Float16* base = (gnt < 4) ? q : (gnt < 8) ? k : v;
        const int chunk = gnt & 3;
        #pragma unroll
        for (int mt = 0; mt < 4; ++mt) {
            const int pxm = px0 + wave_m * 64 + mt * 16 + n;
            const float4v d = acc[tnt][mt];
            f16x2 lo = {(_Float16)d[0], (_Float16)d[1]};
            f16x2 hi = {(_Float16)d[2], (_Float16)d[3]};
            uint2 u;
            __builtin_memcpy(&u.x, &lo, 4);
            __builtin_memcpy(&u.y, &hi, 4);
            *(uint2*)(base + (((size_t)b * 4 + chunk) * HW_ + pxm) * 16 + kg * 4) = u;
        }
    }
}

// ---------------------------------------------------------------------------
// K2: fused local attention — R9 structure + T5 s_setprio(1) around the
// dot2/FMA compute clusters. Mechanism: 2 independent blocks/CU run at
// DIFFERENT phases (one computes while the other stages) — the wave-role
// diversity regime where setprio measured +4-7% on attn (m191), vs null on
// lockstep GEMM (m190). Everything else byte-identical to R9.
// (R11 infra-failed: container died. R12 infra-failed: GPU acquisition
// timeout. Kernel never ran either time — unmodified resubmit #2.)
// ---------------------------------------------------------------------------
#define HP_ 484                 // 22*22 halo pixels
#define PL_ 1948                // words per uint4-plane (484*4 + 12 pad)

__global__ __launch_bounds__(512, 4) void local_attn(
    const _Float16* __restrict__ q, const _Float16* __restrict__ k,
    const _Float16* __restrict__ v, float* __restrict__ out)
{
    __shared__ float tile[8 * PL_];
    const int b = blockIdx.z, h0 = blockIdx.y * 16, w0 = blockIdx.x * 16;
    const int t = threadIdx.x;
    const int lane = t & 63, wave = t >> 6;
    const int g = lane & 1;                      // channel-group: planes g*4..g*4+3
    const int pixel = wave * 32 + (lane >> 1);   // 0..255
    const int pw = pixel & 15, ph = pixel >> 4;
    const size_t px = (size_t)(h0 + ph) * W_ + (w0 + pw);

    // q for own pixel, own 4 planes: 16 VGPR
    uint4 qv[4];
    #pragma unroll
    for (int pp = 0; pp < 4; ++pp) {
        const int p8 = g * 4 + pp;
        qv[pp] = *(const uint4*)(q + (((size_t)b * 4 + (p8 >> 1)) * HW_ + px) * 16 + (p8 & 1) * 8);
    }

    // ---- stage all of k (fp16, 8 planes), 512 threads ----
    for (int i = t; i < HP_ * 8; i += 512) {
        const int pix = i >> 3, c8 = i & 7;
        const int r = pix / 22, cl = pix - r * 22;
        const int gh = h0 + r - 3, gw = w0 + cl - 3;
        uint4 val = make_uint4(0u, 0u, 0u, 0u);
        if (gh >= 0 && gh < H_ && gw >= 0 && gw < W_)
            val = *(const uint4*)(k + (((size_t)b * 4 + (c8 >> 1)) * HW_ +
                                       (size_t)gh * W_ + gw) * 16 + (c8 & 1) * 8);
        *(uint4*)(tile + c8 * PL_ + pix * 4) = val;
    }
    __syncthreads();

    // ---- T14 issue-early: 6/8 of v-halo into registers (24 VGPR) ----
    uint4 vreg[6];
    #pragma unroll
    for (int r = 0; r < 6; ++r) {
        const int i = t + r * 512;               // max 3071 < 3872, no range check
        const int pix = i >> 3, c8 = i & 7;
        const int rr = pix / 22, cl = pix - rr * 22;
        const int gh = h0 + rr - 3, gw = w0 + cl - 3;
        vreg[r] = make_uint4(0u, 0u, 0u, 0u);
        if (gh >= 0 && gh < H_ && gw >= 0 && gw < W_)
            vreg[r] = *(const uint4*)(v + (((size_t)b * 4 + (c8 >> 1)) * HW_ +
                                           (size_t)gh * W_ + gw) * 16 + (c8 & 1) * 8);
    }

    // ---- phase 1: partial scores over own 4 planes (setprio'd) ----
    float sc[49];
    __builtin_amdgcn_s_setprio(1);
    #pragma unroll
    for (int dh = 0; dh < 7; ++dh) {
        #pragma unroll
        for (int dw = 0; dw < 7; ++dw) {
            const int np = ((ph + dh) * 22 + (pw + dw)) * 4;
            float s0 = 0.f, s1 = 0.f, s2 = 0.f, s3 = 0.f;
            #pragma unroll
            for (int pp = 0; pp < 4; ++pp) {
                const uint4 u = *(const uint4*)(tile + (g * 4 + pp) * PL_ + np);
                s0 = dot2(qv[pp].x, u.x, s0);
                s1 = dot2(qv[pp].y, u.y, s1);
                s2 = dot2(qv[pp].z, u.z, s2);
                s3 = dot2(qv[pp].w, u.w, s3);
            }
            sc[dh * 7 + dw] = (s0 + s1) + (s2 + s3);
        }
    }
    __builtin_amdgcn_s_setprio(0);

    // ---- merge pair partials: xor-1 butterfly (in-wave swizzle) ----
    #pragma unroll
    for (int i = 0; i < 49; ++i)
        sc[i] += __shfl_xor(sc[i], 1, 64);

    // ---- softmax over 49 (duplicated per pair) ----
    float m = sc[0];
    #pragma unroll
    for (int i = 1; i < 49; ++i) m = fmaxf(m, sc[i]);
    float s = 0.f;
    #pragma unroll
    for (int i = 0; i < 49; ++i) { sc[i] = __expf(sc[i] - m); s += sc[i]; }
    const float inv = 1.f / s;
    #pragma unroll
    for (int i = 0; i < 49; ++i) sc[i] *= inv;

    __syncthreads();            // all phase-1 reads done before overwrite

    // ---- write-late: 6 prefetched rounds from regs; last 2 load now ----
    #pragma unroll
    for (int r = 0; r < 6; ++r) {
        const int i = t + r * 512;
        const int pix = i >> 3, c8 = i & 7;
        *(uint4*)(tile + c8 * PL_ + pix * 4) = vreg[r];
    }
    for (int i = t + 3072; i < HP_ * 8; i += 512) {
        const int pix = i >> 3, c8 = i & 7;
        const int r = pix / 22, cl = pix - r * 22;
        const int gh = h0 + r - 3, gw = w0 + cl - 3;
        uint4 val = make_uint4(0u, 0u, 0u, 0u);
        if (gh >= 0 && gh < H_ && gw >= 0 && gw < W_)
            val = *(const uint4*)(v + (((size_t)b * 4 + (c8 >> 1)) * HW_ +
                                       (size_t)gh * W_ + gw) * 16 + (c8 & 1) * 8);
        *(uint4*)(tile + c8 * PL_ + pix * 4) = val;
    }
    __syncthreads();

    // ---- phase 2: weighting over own 4 planes (acc[32], setprio'd) ----
    float acc[32];
    #pragma unroll
    for (int c = 0; c < 32; ++c) acc[c] = 0.f;
    __builtin_amdgcn_s_setprio(1);
    #pragma unroll
    for (int dh = 0; dh < 7; ++dh) {
        #pragma unroll
        for (int dw = 0; dw < 7; ++dw) {
            const float wgt = sc[dh * 7 + dw];
            const int np = ((ph + dh) * 22 + (pw + dw)) * 4;
            #pragma unroll
            for (int pp = 0; pp < 4; ++pp) {
                const uint4 u = *(const uint4*)(tile + (g * 4 + pp) * PL_ + np);
                const int a = pp * 8;
                float2 f;
                f = up2(u.x); acc[a + 0] = fmaf(wgt, f.x, acc[a + 0]);
                              acc[a + 1] = fmaf(wgt, f.y, acc[a + 1]);
                f = up2(u.y); acc[a + 2] = fmaf(wgt, f.x, acc[a + 2]);
                              acc[a + 3] = fmaf(wgt, f.y, acc[a + 3]);
                f = up2(u.z); acc[a + 4] = fmaf(wgt, f.x, acc[a + 4]);
                              acc[a + 5] = fmaf(wgt, f.y, acc[a + 5]);
                f = up2(u.w); acc[a + 6] = fmaf(wgt, f.x, acc[a + 6]);
                              acc[a + 7] = fmaf(wgt, f.y, acc[a + 7]);
            }
        }
    }
    __builtin_amdgcn_s_setprio(0);

    // ---- store own 32 channels: [b][64][HW] ----
    #pragma unroll
    for (int pp = 0; pp < 4; ++pp) {
        const int p8 = g * 4 + pp;
        const int ch0 = (p8 >> 1) * 16 + (p8 & 1) * 8;
        #pragma unroll
        for (int j = 0; j < 8; ++j)
            out[((size_t)b * 64 + ch0 + j) * HW_ + px] = acc[pp * 8 + j];
    }
}

extern "C" void kernel_launch(void* const* d_in, const int* in_sizes, int n_in,
                              void* d_out, int out_size, void* d_ws, size_t ws_size,
                              hipStream_t stream) {
    const float* x  = (const float*)d_in[0];
    const float* w1 = (const float*)d_in[1];
    const float* w2 = (const float*)d_in[2];
    const float* w3 = (const float*)d_in[3];

    const size_t NE = (size_t)B_ * 4 * HW_ * 16;   // 8388608 elems per tensor
    _Float16* q = (_Float16*)d_ws;
    _Float16* k = q + NE;
    _Float16* v = k + NE;
    float* o = (float*)d_out;

    proj_qkv<<<dim3(HW_ / 128, B_), 512, 0, stream>>>(x, w1, w2, w3, q, k, v);
    local_attn<<<dim3(W_ / 16, H_ / 16, B_), 512, 0, stream>>>(q, k, v, o);
}